// Round 1
// baseline (503.802 us; speedup 1.0000x reference)
//
#include <hip/hip_runtime.h>
#include <cstddef>
#include <cstdint>

// GCN 3-layer forward, MI355X.
// R16: R15 base + (a) XCD-sharded feature-chunked aggregation: chunk =
// blockIdx%8 == XCD under round-robin dispatch; per-XCD gather slice 3.2MB
// (D=256) / 1.6MB (D=128) -> L2-resident, table fetched ~once instead of
// ~6x. (b) csr4: 4B edges (u16 src | fp16 dinv_src*w) -- N<65536; halves
// edge stream, kills per-edge dinv gather, halves fill RMW stores.
// (c) degw f32 atomics in build_hist + rsqrt folded into scan1 surplus
// blocks; degdinv dispatch deleted; fill writes csr4 directly.
// Final agg128 (log-softmax needs full row) stays unchunked, csr4-ized.

#define GCN_BN_EPS 1e-5f
#define NB_CHUNK 256  // edge chunks; E/256 = 3125 edges/chunk (u8-safe counts)

typedef short v8bf __attribute__((ext_vector_type(8)));
typedef float v4f __attribute__((ext_vector_type(4)));

// ---------------------------------------------------------------- bf16 utils

__device__ __forceinline__ float4 unpack_bf4(uint2 u) {
  float4 r;
  r.x = __uint_as_float(u.x << 16);
  r.y = __uint_as_float(u.x & 0xffff0000u);
  r.z = __uint_as_float(u.y << 16);
  r.w = __uint_as_float(u.y & 0xffff0000u);
  return r;
}
__device__ __forceinline__ uint16_t f2bf(float f) {
  uint32_t u = __float_as_uint(f);
  return (uint16_t)((u + 0x7fffu + ((u >> 16) & 1u)) >> 16);  // RNE
}
__device__ __forceinline__ uint2 pack_bf4(float4 v) {
  uint2 r;
  r.x = (uint32_t)f2bf(v.x) | ((uint32_t)f2bf(v.y) << 16);
  r.y = (uint32_t)f2bf(v.z) | ((uint32_t)f2bf(v.w) << 16);
  return r;
}
__device__ __forceinline__ float f16tof(unsigned int hi16) {
  return (float)__builtin_bit_cast(_Float16, (unsigned short)hi16);
}

// ---------------------------------------------------------------- CSC build

// fused decode + int64-detect + u8 LDS histogram + weighted-degree atomics
__global__ __launch_bounds__(256) void build_hist_kernel(
    const int* __restrict__ ei, const float* __restrict__ ew,
    int* __restrict__ col_, uint2* __restrict__ pk,
    unsigned int* __restrict__ histw, float* __restrict__ degw, int E, int n) {
  extern __shared__ unsigned int h8[];  // nw words, u8-packed
  __shared__ int s_flag;
  const int b = blockIdx.x;
  const int nw = (n + 3) >> 2;
  if (threadIdx.x == 0) {
    int nz = 0;
    for (int k = 1; k < 64; k += 2) nz |= ei[k];
    s_flag = (nz == 0) ? 1 : 0;  // 1 => int64 layout (high dwords zero)
  }
  for (int i = threadIdx.x; i < nw; i += 256) h8[i] = 0u;
  __syncthreads();
  const int flag = s_flag;
  const int per = (E + NB_CHUNK - 1) / NB_CHUNK;
  const int e0 = b * per, e1 = min(e0 + per, E);
  for (int e = e0 + threadIdx.x; e < e1; e += 256) {
    int r, c;
    if (flag) { r = ei[2 * e]; c = ei[2 * (E + e)]; }
    else      { r = ei[e];     c = ei[E + e]; }
    float w = ew[e];
    col_[e] = c;
    pk[e] = make_uint2((unsigned)r, __float_as_uint(w));
    atomicAdd(&h8[c >> 2], 1u << ((c & 3) * 8));
    atomicAdd(&degw[c], w);  // weighted degree (order-nondet ~1ulp, ok)
  }
  __syncthreads();
  for (int i = threadIdx.x; i < nw; i += 256)
    histw[(size_t)b * nw + i] = h8[i];
}

// scan1 (+ conversions + dinv in surplus blocks)
__global__ __launch_bounds__(256) void scan1_conv_kernel(
    const unsigned int* __restrict__ histw, unsigned int* __restrict__ cntw,
    int* __restrict__ bsum, int nw, int nB,
    const float* __restrict__ x, uint16_t* __restrict__ xb,
    const float* __restrict__ W0, uint16_t* __restrict__ W0t,
    const float* __restrict__ W1, uint16_t* __restrict__ W1t,
    const float* __restrict__ Wl, uint16_t* __restrict__ Wlt,
    const float* __restrict__ degw, float* __restrict__ dinv,
    int t0, int convTot) {
  if (blockIdx.x >= nB) {  // conversion part
    int i = (blockIdx.x - nB) * 256 + threadIdx.x;
    if (i >= convTot) return;
    if (i < t0) {
      float4 v = *(const float4*)&x[(size_t)i * 4];
      *(uint2*)&xb[(size_t)i * 4] = pack_bf4(v);
      return;
    }
    int j = i - t0;
    if (j < 128 * 256) { int nn = j >> 7, k = j & 127; W0t[j] = f2bf(W0[(size_t)k * 256 + nn]); return; }
    j -= 128 * 256;
    if (j < 256 * 256) { int nn = j >> 8, k = j & 255; W1t[j] = f2bf(W1[(size_t)k * 256 + nn]); return; }
    j -= 256 * 256;
    if (j < 256 * 128) { int nn = j >> 8, k = j & 255; Wlt[j] = f2bf(Wl[(size_t)k * 128 + nn]); return; }
    j -= 256 * 128;
    dinv[j] = rsqrtf(1.0f + degw[j]);  // deg = 1 (self) + sum w
    return;
  }
  __shared__ int ws[4];
  const int j = blockIdx.x * 256 + threadIdx.x;
  unsigned int acc = 0;
  if (j < nw)
    for (int b = 0; b < NB_CHUNK; ++b) acc += histw[(size_t)b * nw + j];
  if (j < nw) cntw[j] = acc;
  int s = (int)((acc & 0xffu) + ((acc >> 8) & 0xffu) + ((acc >> 16) & 0xffu) + (acc >> 24));
  int x_ = s;
#pragma unroll
  for (int st = 1; st < 64; st <<= 1) x_ += __shfl_xor(x_, st, 64);
  if ((threadIdx.x & 63) == 0) ws[threadIdx.x >> 6] = x_;
  __syncthreads();
  if (threadIdx.x == 0) bsum[blockIdx.x] = ws[0] + ws[1] + ws[2] + ws[3];
}

// scan3+base (unchanged)
__global__ __launch_bounds__(256) void scan3_base_kernel(
    const unsigned int* __restrict__ cntw, const int* __restrict__ bsum,
    int* __restrict__ off, unsigned int* __restrict__ histw,
    int nw, int nB, int n, int E) {
  __shared__ int wsum[4], woff[4];
  __shared__ int s_gbase;
  const int tid = threadIdx.x, lane = tid & 63, wv = tid >> 6;
  const int j = blockIdx.x * 256 + tid;
  unsigned int cw = (j < nw) ? cntw[j] : 0u;
  const int c0 = (int)(cw & 0xffu), c1 = (int)((cw >> 8) & 0xffu);
  const int c2 = (int)((cw >> 16) & 0xffu), c3 = (int)(cw >> 24);
  int s = c0 + c1 + c2 + c3;
  int x = s;
#pragma unroll
  for (int st = 1; st < 64; st <<= 1) { int t = __shfl_up(x, st, 64); if (lane >= st) x += t; }
  if (lane == 63) wsum[wv] = x;
  __syncthreads();
  if (tid == 0) { int r = 0; for (int k = 0; k < 4; ++k) { woff[k] = r; r += wsum[k]; } }
  if (wv == 0) {  // inline exclusive scan of bsum[0..nB) (nB <= 64)
    int v2 = (lane < nB) ? bsum[lane] : 0;
    int y = v2;
#pragma unroll
    for (int st = 1; st < 64; st <<= 1) { int t = __shfl_up(y, st, 64); if (lane >= st) y += t; }
    if (lane == blockIdx.x) s_gbase = y - v2;
  }
  __syncthreads();
  if (j < nw) {
    int excl = x - s + woff[wv] + s_gbase;
    uint4 o4;
    o4.x = excl; o4.y = excl + c0; o4.z = excl + c0 + c1; o4.w = excl + c0 + c1 + c2;
    *(uint4*)&off[4 * j] = o4;  // n % 4 == 0 assumed (n = 50000)
    unsigned int run = 0;
    for (int b = 0; b < NB_CHUNK; ++b) {
      size_t idx = (size_t)b * nw + j;
      unsigned int w = histw[idx];
      histw[idx] = run;
      run += w;
    }
  }
  if (blockIdx.x == 0 && tid == 0) off[n] = E;
}

// fill: writes csr4 = (u16 src | f16 dinv_src*w) directly (4B scattered RMW)
__global__ __launch_bounds__(256) void fill_kernel(
    const int* __restrict__ col_, const uint2* __restrict__ pk,
    const int* __restrict__ off, const unsigned int* __restrict__ histw,
    const float* __restrict__ dinv, unsigned int* __restrict__ csr4,
    int E, int n) {
  extern __shared__ unsigned int c8[];  // nw words, u8-packed counters
  const int b = blockIdx.x;
  const int nw = (n + 3) >> 2;
  for (int i = threadIdx.x; i < nw; i += 256) c8[i] = 0u;
  __syncthreads();
  const int per = (E + NB_CHUNK - 1) / NB_CHUNK;
  const int e0 = b * per, e1 = min(e0 + per, E);
  const unsigned int* brel = histw + (size_t)b * nw;  // 50KB slice, L2-resident
  for (int e = e0 + threadIdx.x; e < e1; e += 256) {
    int c = col_[e];
    const int sh = (c & 3) * 8;
    unsigned old = atomicAdd(&c8[c >> 2], 1u << sh);
    int rel = (int)((old >> sh) & 0xffu) + (int)((brel[c >> 2] >> sh) & 0xffu);
    uint2 v = pk[e];
    float nv = dinv[(int)v.x] * __uint_as_float(v.y);  // dinv gather: 200KB, L2
    unsigned short hb = __builtin_bit_cast(unsigned short, (_Float16)nv);
    csr4[off[c] + rel] = (v.x & 0xffffu) | ((unsigned int)hb << 16);
  }
}

// ---------------------------------------------------------------- aggregation
// acc = dinv_c*(dinv_c*h_c + sum f16(dinv_s*w)*h_s), csr4 4B/edge.

// XCD-sharded chunked agg: chunk = blockIdx%8 (== XCD under round-robin).
// Each XCD gathers only from its CH-feature slice (N*CH*2B, L2-resident).
// SUB lanes per node, 4 feats (8B) per lane. EPI 0 plain, 1 +bias+BN+ReLU.
template <int D, int CH, int SUB, int EPI>
__global__ __launch_bounds__(256) void aggc_kernel(
    const uint16_t* __restrict__ hin, uint16_t* __restrict__ hout,
    const int* __restrict__ off, const unsigned int* __restrict__ csr4,
    const float* __restrict__ dinv, const float* __restrict__ bias,
    const float* __restrict__ g, const float* __restrict__ be, int n) {
  static_assert(D == CH * 8 && SUB * 4 == CH, "8 chunks, 4 feats/lane");
  const int chunk = blockIdx.x & 7;   // XCD id under round-robin dispatch
  const int nblk = blockIdx.x >> 3;
  constexpr int NPW = 64 / SUB;       // nodes per wave
  const int lane = threadIdx.x & 63;
  const int ls = lane & (SUB - 1);
  const int sb = lane & ~(SUB - 1);
  const int c = (nblk * 4 + (threadIdx.x >> 6)) * NPW + (lane / SUB);
  if (c >= n) return;
  const int fo = chunk * CH + ls * 4;
  const float di = dinv[c];
  float4 acc = unpack_bf4(*(const uint2*)&hin[(size_t)c * D + fo]);
  acc.x *= di; acc.y *= di; acc.z *= di; acc.w *= di;
  const int e0 = off[c], e1 = off[c + 1];
  for (int base = e0; base < e1; base += SUB) {
    int idx = base + ls;
    unsigned int ev = (idx < e1) ? __builtin_nontemporal_load(&csr4[idx]) : 0u;
    const int m = min(SUB, e1 - base);
    if (m == SUB) {
#pragma unroll
      for (int j = 0; j < SUB; ++j) {
        unsigned int e = __shfl(ev, sb + j, 64);
        float nv = f16tof(e >> 16);
        float4 h = unpack_bf4(*(const uint2*)&hin[(size_t)(e & 0xffffu) * D + fo]);
        acc.x += nv * h.x; acc.y += nv * h.y;
        acc.z += nv * h.z; acc.w += nv * h.w;
      }
    } else {
      for (int j = 0; j < m; ++j) {
        unsigned int e = __shfl(ev, sb + j, 64);
        float nv = f16tof(e >> 16);
        float4 h = unpack_bf4(*(const uint2*)&hin[(size_t)(e & 0xffffu) * D + fo]);
        acc.x += nv * h.x; acc.y += nv * h.y;
        acc.z += nv * h.z; acc.w += nv * h.w;
      }
    }
  }
  acc.x *= di; acc.y *= di; acc.z *= di; acc.w *= di;  // final dinv_c
  if (EPI == 1) {
    const float bns = rsqrtf(1.0f + GCN_BN_EPS);
    float4 bi = *(const float4*)&bias[fo];
    float4 gi = *(const float4*)&g[fo];
    float4 bei = *(const float4*)&be[fo];
    acc.x = fmaxf((acc.x + bi.x) * gi.x * bns + bei.x, 0.0f);
    acc.y = fmaxf((acc.y + bi.y) * gi.y * bns + bei.y, 0.0f);
    acc.z = fmaxf((acc.z + bi.z) * gi.z * bns + bei.z, 0.0f);
    acc.w = fmaxf((acc.w + bi.w) * gi.w * bns + bei.w, 0.0f);
  }
  uint2 pv = pack_bf4(acc);
  unsigned long long v64 = (unsigned long long)pv.x | ((unsigned long long)pv.y << 32);
  __builtin_nontemporal_store(v64, (unsigned long long*)&hout[(size_t)c * D + fo]);
}

// D=128 unchunked (final layer: log_softmax needs full row). csr4 edges.
// EPI 2: +bias, log_softmax -> fp32 out.
template <int EPI>
__global__ __launch_bounds__(256) void agg128_kernel(
    const uint16_t* __restrict__ hin, void* __restrict__ hout_,
    const int* __restrict__ off, const unsigned int* __restrict__ csr4,
    const float* __restrict__ dinv, const float* __restrict__ bias, int n) {
  const int lane = threadIdx.x & 63;
  const int sub = lane & 31;
  const int hbase = lane & 32;
  const int c = blockIdx.x * 8 + (threadIdx.x >> 6) * 2 + (lane >> 5);
  const bool active = (c < n);
  const int f = sub * 4;

  int e0 = 0, e1 = 0;
  float di = 0.0f;
  float4 acc = make_float4(0.f, 0.f, 0.f, 0.f);
  if (active) {
    e0 = off[c]; e1 = off[c + 1];
    di = dinv[c];
    float4 self = unpack_bf4(*(const uint2*)&hin[(size_t)c * 128 + f]);
    acc = make_float4(self.x * di, self.y * di, self.z * di, self.w * di);
  }
  int nch = (e1 - e0 + 31) >> 5;
  nch = max(nch, __shfl(nch, lane ^ 32));

  for (int ch = 0; ch < nch; ++ch) {
    int idx = e0 + ch * 32 + sub;
    unsigned int ev = 0u;
    if (active && idx < e1) ev = __builtin_nontemporal_load(&csr4[idx]);
    int m = e1 - (e0 + ch * 32);
    m = m < 0 ? 0 : (m > 32 ? 32 : m);
    int mMax = max(m, __shfl(m, lane ^ 32));
    const int nG = (mMax + 3) >> 2;
    for (int gI = 0; gI < nG; ++gI) {
      int e_ = hbase + gI * 4;
      unsigned int ea = __shfl(ev, e_, 64);
      unsigned int eb = __shfl(ev, e_ + 1, 64);
      unsigned int ec = __shfl(ev, e_ + 2, 64);
      unsigned int ed = __shfl(ev, e_ + 3, 64);
      int s0 = (int)(ea & 0xffffu); float v0 = f16tof(ea >> 16);
      int s1 = (int)(eb & 0xffffu); float v1 = f16tof(eb >> 16);
      int sB = (int)(ec & 0xffffu); float v2 = f16tof(ec >> 16);
      int s3 = (int)(ed & 0xffffu); float v3 = f16tof(ed >> 16);
      float4 h0 = unpack_bf4(*(const uint2*)&hin[(size_t)s0 * 128 + f]);
      float4 h1 = unpack_bf4(*(const uint2*)&hin[(size_t)s1 * 128 + f]);
      float4 h2 = unpack_bf4(*(const uint2*)&hin[(size_t)sB * 128 + f]);
      float4 h3 = unpack_bf4(*(const uint2*)&hin[(size_t)s3 * 128 + f]);
      acc.x += v0 * h0.x + v1 * h1.x + v2 * h2.x + v3 * h3.x;
      acc.y += v0 * h0.y + v1 * h1.y + v2 * h2.y + v3 * h3.y;
      acc.z += v0 * h0.z + v1 * h1.z + v2 * h2.z + v3 * h3.z;
      acc.w += v0 * h0.w + v1 * h1.w + v2 * h2.w + v3 * h3.w;
    }
  }

  acc.x *= di; acc.y *= di; acc.z *= di; acc.w *= di;  // final dinv_c
  if (EPI == 0) {
    uint16_t* hout = (uint16_t*)hout_;
    if (active) *(uint2*)&hout[(size_t)c * 128 + f] = pack_bf4(acc);
  } else {
    float* hout = (float*)hout_;
    float4 bi = active ? *(const float4*)&bias[f] : make_float4(0.f, 0.f, 0.f, 0.f);
    float tx = acc.x + bi.x, ty = acc.y + bi.y, tz = acc.z + bi.z, tw = acc.w + bi.w;
    float mx = fmaxf(fmaxf(tx, ty), fmaxf(tz, tw));
#pragma unroll
    for (int s = 1; s < 32; s <<= 1) mx = fmaxf(mx, __shfl_xor(mx, s, 64));
    float ex = expf(tx - mx) + expf(ty - mx) + expf(tz - mx) + expf(tw - mx);
#pragma unroll
    for (int s = 1; s < 32; s <<= 1) ex += __shfl_xor(ex, s, 64);
    float lse = logf(ex) + mx;
    if (active) {
      float4 res = make_float4(tx - lse, ty - lse, tz - lse, tw - lse);
      *(float4*)&hout[(size_t)c * 128 + f] = res;
    }
  }
}

// ---------------------------------------------------------------- MFMA GEMM
// B-stationary: wave holds B-frags for its col group across all K in registers,
// streams 16-row A-tiles with depth-2 prefetch; 4 waves/block share A rows.
template <int K, int NC, int EPI>
__global__ __launch_bounds__(256) void mfma_gemm_kernel(
    const uint16_t* __restrict__ A, const uint16_t* __restrict__ WT,
    uint16_t* __restrict__ Cb, int M, int tpb,
    const float* __restrict__ bias, const float* __restrict__ g,
    const float* __restrict__ be) {
  constexpr int CW = NC / 4;
  constexpr int NT = CW / 16;
  constexpr int KS = K / 32;
  const int lane = threadIdx.x & 63;
  const int wave = threadIdx.x >> 6;
  const int quad = lane >> 4;
  const int l16 = lane & 15;
  const int col0 = wave * CW;

  const int tiles = (M + 15) >> 4;
  int t0 = blockIdx.x * tpb;
  if (t0 >= tiles) return;
  int t1 = min(t0 + tpb, tiles);

  v8bf b[KS][NT];
#pragma unroll
  for (int ks = 0; ks < KS; ++ks)
#pragma unroll
    for (int nt = 0; nt < NT; ++nt)
      b[ks][nt] = *(const v8bf*)(WT + (size_t)(col0 + nt * 16 + l16) * K +
                                 ks * 32 + quad * 8);

  float sc[NT], o1[NT], o2[NT];
  if (EPI == 1) {
    const float bns = rsqrtf(1.0f + GCN_BN_EPS);
#pragma unroll
    for (int nt = 0; nt < NT; ++nt) {
      int col = col0 + nt * 16 + l16;
      sc[nt] = g[col] * bns; o1[nt] = bias[col]; o2[nt] = be[col];
    }
  }

  v8bf a[KS], an[KS];
  {
    int arow = min(t0 * 16 + l16, M - 1);
    const uint16_t* Ap = A + (size_t)arow * K + quad * 8;
#pragma unroll
    for (int ks = 0; ks < KS; ++ks) a[ks] = *(const v8bf*)(Ap + ks * 32);
  }
  for (int t = t0; t < t1; ++t) {
    if (t + 1 < t1) {
      int arow = min((t + 1) * 16 + l16, M - 1);
      const uint16_t* Ap = A + (size_t)arow * K + quad * 8;
#pragma unroll
      for (int ks = 0; ks < KS; ++ks) an[ks] = *(const v8bf*)(Ap + ks * 32);
    }
    v4f acc[NT];
#pragma unroll
    for (int nt = 0; nt < NT; ++nt) acc[nt] = (v4f){0.f, 0.f, 0.f, 0.f};
#pragma unroll
    for (int ks = 0; ks < KS; ++ks)
#pragma unroll
      for (int nt = 0; nt < NT; ++nt)
        acc[nt] = __builtin_amdgcn_mfma_f32_16x16x32_bf16(a[ks], b[ks][nt],
                                                          acc[nt], 0, 0, 0);
    const int row0 = t * 16 + quad * 4;
#pragma unroll
    for (int nt = 0; nt < NT; ++nt) {
      const int col = col0 + nt * 16 + l16;
#pragma unroll
      for (int r = 0; r < 4; ++r) {
        int row = row0 + r;
        if (row < M) {
          float v = acc[nt][r];
          if (EPI == 1) v = fmaxf((v + o1[nt]) * sc[nt] + o2[nt], 0.0f);
          Cb[(size_t)row * NC + col] = f2bf(v);
        }
      }
    }
#pragma unroll
    for (int ks = 0; ks < KS; ++ks) a[ks] = an[ks];
  }
}

// ---------------------------------------------------------------- launch

static inline char* carve(char*& p, size_t bytes) {
  char* r = p;
  p += (bytes + 255) & ~(size_t)255;
  return r;
}

extern "C" void kernel_launch(void* const* d_in, const int* in_sizes, int n_in,
                              void* d_out, int out_size, void* d_ws, size_t ws_size,
                              hipStream_t stream) {
  const int N = in_sizes[0] / 128;
  const int E = in_sizes[2];

  const float* x  = (const float*)d_in[0];
  const int*   ei = (const int*)d_in[1];
  const float* ew = (const float*)d_in[2];
  const float* W0 = (const float*)d_in[3];
  const float* b0 = (const float*)d_in[4];
  const float* W1 = (const float*)d_in[5];
  const float* b1 = (const float*)d_in[6];
  const float* Wl = (const float*)d_in[7];
  const float* bl = (const float*)d_in[8];
  const float* g0 = (const float*)d_in[9];
  const float* be0 = (const float*)d_in[10];
  const float* g1 = (const float*)d_in[11];
  const float* be1 = (const float*)d_in[12];
  float* out = (float*)d_out;

  const int nw = (N + 3) / 4;  // histogram words (N % 4 == 0 for N=50000)

  char* p = (char*)d_ws;
  float*        dinv  = (float*)carve(p, (size_t)N * 4);
  float*        degw  = (float*)carve(p, (size_t)N * 4);
  unsigned int* cntw  = (unsigned int*)carve(p, (size_t)nw * 4);
  int*          off   = (int*)carve(p, (size_t)(N + 1) * 4);
  int*          bsum  = (int*)carve(p, 1024 * 4);
  int*          col_  = (int*)carve(p, (size_t)E * 4);
  uint2*        pk    = (uint2*)carve(p, (size_t)E * 8);
  unsigned int* csr4  = (unsigned int*)carve(p, (size_t)E * 4);
  unsigned int* histw = (unsigned int*)carve(p, (size_t)NB_CHUNK * nw * 4);
  uint16_t*     xb16  = (uint16_t*)carve(p, (size_t)N * 128 * 2);
  uint16_t*     bufR  = (uint16_t*)carve(p, (size_t)N * 128 * 2);
  uint16_t*     bufP  = (uint16_t*)carve(p, (size_t)N * 256 * 2);
  uint16_t*     bufQ  = (uint16_t*)carve(p, (size_t)N * 256 * 2);
  uint16_t*     W0t   = (uint16_t*)carve(p, (size_t)128 * 256 * 2);
  uint16_t*     W1t   = (uint16_t*)carve(p, (size_t)256 * 256 * 2);
  uint16_t*     Wlt   = (uint16_t*)carve(p, (size_t)256 * 128 * 2);

  const int TB = 256;
  const int gW8 = (N + 7) / 8;          // final agg128: 8 nodes/block
  const int nbA = (N + 63) / 64;        // aggc<128>: 64 nodes/block
  const int nbB = (N + 31) / 32;        // aggc<256>: 32 nodes/block
  const int tiles = (N + 15) / 16;
  const int TPB = 8;                    // row-tiles per block
  const int gG = (tiles + TPB - 1) / TPB;
  const size_t ldsU8 = (size_t)nw * 4;  // 50KB u8-packed bins
  const int nB = (nw + 255) / 256;      // scan blocks (49 <= 64, required)
  const int convT0 = N * 32;            // x float4 groups
  const int convTot = convT0 + 128 * 256 + 256 * 256 + 256 * 128 + N;  // +dinv
  const int convB = (convTot + TB - 1) / TB;

  // CSC build: u8-chunked build (+degw atomics), scan+conv+dinv, fused
  // scan3+base, single-pass fill writing csr4 (u16 src | f16 dinv_s*w)
  hipMemsetAsync(degw, 0, (size_t)N * 4, stream);
  build_hist_kernel<<<NB_CHUNK, TB, ldsU8, stream>>>(ei, ew, col_, pk, histw,
                                                     degw, E, N);
  scan1_conv_kernel<<<nB + convB, TB, 0, stream>>>(histw, cntw, bsum, nw, nB,
                                                   x, xb16, W0, W0t, W1, W1t,
                                                   Wl, Wlt, degw, dinv,
                                                   convT0, convTot);
  scan3_base_kernel<<<nB, TB, 0, stream>>>(cntw, bsum, off, histw, nw, nB, N, E);
  fill_kernel<<<NB_CHUNK, TB, ldsU8, stream>>>(col_, pk, off, histw, dinv,
                                               csr4, E, N);

  // layer 0: XCD-chunked agg(xb16,128) -> bufR; GEMM0 +BN0+ReLU -> bufP
  aggc_kernel<128, 16, 4, 0><<<nbA * 8, 256, 0, stream>>>(
      xb16, bufR, off, csr4, dinv, nullptr, nullptr, nullptr, N);
  mfma_gemm_kernel<128, 256, 1><<<gG, 256, 0, stream>>>(bufR, W0t, bufP, N, TPB,
                                                        b0, g0, be0);
  // layer 1: GEMM1 -> bufQ; XCD-chunked agg256 +b1+BN1+ReLU -> bufP
  mfma_gemm_kernel<256, 256, 0><<<gG, 256, 0, stream>>>(bufP, W1t, bufQ, N, TPB,
                                                        nullptr, nullptr, nullptr);
  aggc_kernel<256, 32, 8, 1><<<nbB * 8, 256, 0, stream>>>(
      bufQ, bufP, off, csr4, dinv, b1, g1, be1, N);
  // layer 2: GEMM2 -> bufR; agg128 +bl+log_softmax -> out (fp32)
  mfma_gemm_kernel<256, 128, 0><<<gG, 256, 0, stream>>>(bufP, Wlt, bufR, N, TPB,
                                                        nullptr, nullptr, nullptr);
  agg128_kernel<2><<<gW8, 256, 0, stream>>>(bufR, out, off, csr4, dinv, bl, N);
}

// Round 2
// 385.569 us; speedup vs baseline: 1.3066x; 1.3066x over previous
//
#include <hip/hip_runtime.h>
#include <cstddef>
#include <cstdint>

// GCN 3-layer forward, MI355X.
// R17: revert R16's XCD-chunked aggregation (mapping %8->XCD does not hold
// in steady state: FETCH stayed 200MB, 8B gathers tanked line utilization,
// 60->107us). Back to R15's coalesced full-row agg (wave/node D=256,
// half-wave/node D=128, 4 feats/lane) -- the 3.7 TB/s fill pattern.
// KEEP R16's independent wins: csr4 4B edges (u16 src | f16 dinv_s*w),
// degw atomics in build_hist + rsqrt folded into scan1 (degdinv dispatch
// deleted), fill writes csr4 directly, nontemporal csr stream loads.

#define GCN_BN_EPS 1e-5f
#define NB_CHUNK 256  // edge chunks; E/256 = 3125 edges/chunk (u8-safe counts)

typedef short v8bf __attribute__((ext_vector_type(8)));
typedef float v4f __attribute__((ext_vector_type(4)));

// ---------------------------------------------------------------- bf16 utils

__device__ __forceinline__ float4 unpack_bf4(uint2 u) {
  float4 r;
  r.x = __uint_as_float(u.x << 16);
  r.y = __uint_as_float(u.x & 0xffff0000u);
  r.z = __uint_as_float(u.y << 16);
  r.w = __uint_as_float(u.y & 0xffff0000u);
  return r;
}
__device__ __forceinline__ uint16_t f2bf(float f) {
  uint32_t u = __float_as_uint(f);
  return (uint16_t)((u + 0x7fffu + ((u >> 16) & 1u)) >> 16);  // RNE
}
__device__ __forceinline__ uint2 pack_bf4(float4 v) {
  uint2 r;
  r.x = (uint32_t)f2bf(v.x) | ((uint32_t)f2bf(v.y) << 16);
  r.y = (uint32_t)f2bf(v.z) | ((uint32_t)f2bf(v.w) << 16);
  return r;
}
__device__ __forceinline__ float f16tof(unsigned int hi16) {
  return (float)__builtin_bit_cast(_Float16, (unsigned short)hi16);
}

// ---------------------------------------------------------------- CSC build

// fused decode + int64-detect + u8 LDS histogram + weighted-degree atomics
__global__ __launch_bounds__(256) void build_hist_kernel(
    const int* __restrict__ ei, const float* __restrict__ ew,
    int* __restrict__ col_, uint2* __restrict__ pk,
    unsigned int* __restrict__ histw, float* __restrict__ degw, int E, int n) {
  extern __shared__ unsigned int h8[];  // nw words, u8-packed
  __shared__ int s_flag;
  const int b = blockIdx.x;
  const int nw = (n + 3) >> 2;
  if (threadIdx.x == 0) {
    int nz = 0;
    for (int k = 1; k < 64; k += 2) nz |= ei[k];
    s_flag = (nz == 0) ? 1 : 0;  // 1 => int64 layout (high dwords zero)
  }
  for (int i = threadIdx.x; i < nw; i += 256) h8[i] = 0u;
  __syncthreads();
  const int flag = s_flag;
  const int per = (E + NB_CHUNK - 1) / NB_CHUNK;
  const int e0 = b * per, e1 = min(e0 + per, E);
  for (int e = e0 + threadIdx.x; e < e1; e += 256) {
    int r, c;
    if (flag) { r = ei[2 * e]; c = ei[2 * (E + e)]; }
    else      { r = ei[e];     c = ei[E + e]; }
    float w = ew[e];
    col_[e] = c;
    pk[e] = make_uint2((unsigned)r, __float_as_uint(w));
    atomicAdd(&h8[c >> 2], 1u << ((c & 3) * 8));
    atomicAdd(&degw[c], w);  // weighted degree (order-nondet ~1ulp, ok)
  }
  __syncthreads();
  for (int i = threadIdx.x; i < nw; i += 256)
    histw[(size_t)b * nw + i] = h8[i];
}

// scan1 (+ conversions + dinv in surplus blocks)
__global__ __launch_bounds__(256) void scan1_conv_kernel(
    const unsigned int* __restrict__ histw, unsigned int* __restrict__ cntw,
    int* __restrict__ bsum, int nw, int nB,
    const float* __restrict__ x, uint16_t* __restrict__ xb,
    const float* __restrict__ W0, uint16_t* __restrict__ W0t,
    const float* __restrict__ W1, uint16_t* __restrict__ W1t,
    const float* __restrict__ Wl, uint16_t* __restrict__ Wlt,
    const float* __restrict__ degw, float* __restrict__ dinv,
    int t0, int convTot) {
  if (blockIdx.x >= nB) {  // conversion part
    int i = (blockIdx.x - nB) * 256 + threadIdx.x;
    if (i >= convTot) return;
    if (i < t0) {
      float4 v = *(const float4*)&x[(size_t)i * 4];
      *(uint2*)&xb[(size_t)i * 4] = pack_bf4(v);
      return;
    }
    int j = i - t0;
    if (j < 128 * 256) { int nn = j >> 7, k = j & 127; W0t[j] = f2bf(W0[(size_t)k * 256 + nn]); return; }
    j -= 128 * 256;
    if (j < 256 * 256) { int nn = j >> 8, k = j & 255; W1t[j] = f2bf(W1[(size_t)k * 256 + nn]); return; }
    j -= 256 * 256;
    if (j < 256 * 128) { int nn = j >> 8, k = j & 255; Wlt[j] = f2bf(Wl[(size_t)k * 128 + nn]); return; }
    j -= 256 * 128;
    dinv[j] = rsqrtf(1.0f + degw[j]);  // deg = 1 (self) + sum w
    return;
  }
  __shared__ int ws[4];
  const int j = blockIdx.x * 256 + threadIdx.x;
  unsigned int acc = 0;
  if (j < nw)
    for (int b = 0; b < NB_CHUNK; ++b) acc += histw[(size_t)b * nw + j];
  if (j < nw) cntw[j] = acc;
  int s = (int)((acc & 0xffu) + ((acc >> 8) & 0xffu) + ((acc >> 16) & 0xffu) + (acc >> 24));
  int x_ = s;
#pragma unroll
  for (int st = 1; st < 64; st <<= 1) x_ += __shfl_xor(x_, st, 64);
  if ((threadIdx.x & 63) == 0) ws[threadIdx.x >> 6] = x_;
  __syncthreads();
  if (threadIdx.x == 0) bsum[blockIdx.x] = ws[0] + ws[1] + ws[2] + ws[3];
}

// scan3+base (unchanged)
__global__ __launch_bounds__(256) void scan3_base_kernel(
    const unsigned int* __restrict__ cntw, const int* __restrict__ bsum,
    int* __restrict__ off, unsigned int* __restrict__ histw,
    int nw, int nB, int n, int E) {
  __shared__ int wsum[4], woff[4];
  __shared__ int s_gbase;
  const int tid = threadIdx.x, lane = tid & 63, wv = tid >> 6;
  const int j = blockIdx.x * 256 + tid;
  unsigned int cw = (j < nw) ? cntw[j] : 0u;
  const int c0 = (int)(cw & 0xffu), c1 = (int)((cw >> 8) & 0xffu);
  const int c2 = (int)((cw >> 16) & 0xffu), c3 = (int)(cw >> 24);
  int s = c0 + c1 + c2 + c3;
  int x = s;
#pragma unroll
  for (int st = 1; st < 64; st <<= 1) { int t = __shfl_up(x, st, 64); if (lane >= st) x += t; }
  if (lane == 63) wsum[wv] = x;
  __syncthreads();
  if (tid == 0) { int r = 0; for (int k = 0; k < 4; ++k) { woff[k] = r; r += wsum[k]; } }
  if (wv == 0) {  // inline exclusive scan of bsum[0..nB) (nB <= 64)
    int v2 = (lane < nB) ? bsum[lane] : 0;
    int y = v2;
#pragma unroll
    for (int st = 1; st < 64; st <<= 1) { int t = __shfl_up(y, st, 64); if (lane >= st) y += t; }
    if (lane == blockIdx.x) s_gbase = y - v2;
  }
  __syncthreads();
  if (j < nw) {
    int excl = x - s + woff[wv] + s_gbase;
    uint4 o4;
    o4.x = excl; o4.y = excl + c0; o4.z = excl + c0 + c1; o4.w = excl + c0 + c1 + c2;
    *(uint4*)&off[4 * j] = o4;  // n % 4 == 0 assumed (n = 50000)
    unsigned int run = 0;
    for (int b = 0; b < NB_CHUNK; ++b) {
      size_t idx = (size_t)b * nw + j;
      unsigned int w = histw[idx];
      histw[idx] = run;
      run += w;
    }
  }
  if (blockIdx.x == 0 && tid == 0) off[n] = E;
}

// fill: writes csr4 = (u16 src | f16 dinv_src*w) directly (4B scattered RMW)
__global__ __launch_bounds__(256) void fill_kernel(
    const int* __restrict__ col_, const uint2* __restrict__ pk,
    const int* __restrict__ off, const unsigned int* __restrict__ histw,
    const float* __restrict__ dinv, unsigned int* __restrict__ csr4,
    int E, int n) {
  extern __shared__ unsigned int c8[];  // nw words, u8-packed counters
  const int b = blockIdx.x;
  const int nw = (n + 3) >> 2;
  for (int i = threadIdx.x; i < nw; i += 256) c8[i] = 0u;
  __syncthreads();
  const int per = (E + NB_CHUNK - 1) / NB_CHUNK;
  const int e0 = b * per, e1 = min(e0 + per, E);
  const unsigned int* brel = histw + (size_t)b * nw;  // 50KB slice, L2-resident
  for (int e = e0 + threadIdx.x; e < e1; e += 256) {
    int c = col_[e];
    const int sh = (c & 3) * 8;
    unsigned old = atomicAdd(&c8[c >> 2], 1u << sh);
    int rel = (int)((old >> sh) & 0xffu) + (int)((brel[c >> 2] >> sh) & 0xffu);
    uint2 v = pk[e];
    float nv = dinv[(int)v.x] * __uint_as_float(v.y);  // dinv gather: 200KB, L2
    unsigned short hb = __builtin_bit_cast(unsigned short, (_Float16)nv);
    csr4[off[c] + rel] = (v.x & 0xffffu) | ((unsigned int)hb << 16);
  }
}

// ---------------------------------------------------------------- aggregation
// acc = dinv_c*(dinv_c*h_c + sum f16(dinv_s*w)*h_s), csr4 4B/edge.
// Coalesced full-row gathers: every fetched line fully consumed by the wave.

// D=256: one wave per node, lane holds 4 feats (8B). EPI 0 plain, 1 +b+BN+ReLU
template <int EPI>
__global__ __launch_bounds__(256) void agg256_kernel(
    const uint16_t* __restrict__ hin, uint16_t* __restrict__ hout,
    const int* __restrict__ off, const unsigned int* __restrict__ csr4,
    const float* __restrict__ dinv,
    const float* __restrict__ bias, const float* __restrict__ g,
    const float* __restrict__ be, int n) {
  const int lane = threadIdx.x & 63;
  const int c = blockIdx.x * 4 + (threadIdx.x >> 6);
  if (c >= n) return;
  const int f = lane * 4;
  const int e0 = off[c], e1 = off[c + 1];
  const float di = dinv[c];
  float4 self = unpack_bf4(*(const uint2*)&hin[(size_t)c * 256 + f]);
  float4 acc = make_float4(self.x * di, self.y * di, self.z * di, self.w * di);

  for (int base = e0; base < e1; base += 64) {
    int idx = base + lane;
    // zero-pad: ev=0 -> src 0, f16 val 0 (contributes nothing)
    unsigned int ev = (idx < e1) ? __builtin_nontemporal_load(&csr4[idx]) : 0u;
    const int m = min(64, e1 - base);
    const int nG = (m + 3) >> 2;
    for (int gI = 0; gI < nG; ++gI) {
      int e_ = gI * 4;
      unsigned int ea = __shfl(ev, e_, 64);
      unsigned int eb = __shfl(ev, e_ + 1, 64);
      unsigned int ec = __shfl(ev, e_ + 2, 64);
      unsigned int ed = __shfl(ev, e_ + 3, 64);
      float v0 = f16tof(ea >> 16), v1 = f16tof(eb >> 16);
      float v2 = f16tof(ec >> 16), v3 = f16tof(ed >> 16);
      float4 h0 = unpack_bf4(*(const uint2*)&hin[(size_t)(ea & 0xffffu) * 256 + f]);
      float4 h1 = unpack_bf4(*(const uint2*)&hin[(size_t)(eb & 0xffffu) * 256 + f]);
      float4 h2 = unpack_bf4(*(const uint2*)&hin[(size_t)(ec & 0xffffu) * 256 + f]);
      float4 h3 = unpack_bf4(*(const uint2*)&hin[(size_t)(ed & 0xffffu) * 256 + f]);
      acc.x += v0 * h0.x + v1 * h1.x + v2 * h2.x + v3 * h3.x;
      acc.y += v0 * h0.y + v1 * h1.y + v2 * h2.y + v3 * h3.y;
      acc.z += v0 * h0.z + v1 * h1.z + v2 * h2.z + v3 * h3.z;
      acc.w += v0 * h0.w + v1 * h1.w + v2 * h2.w + v3 * h3.w;
    }
  }

  acc.x *= di; acc.y *= di; acc.z *= di; acc.w *= di;  // final dinv_c
  if (EPI == 1) {
    const float bns = rsqrtf(1.0f + GCN_BN_EPS);
    float4 bi = *(const float4*)&bias[f];
    float4 gi = *(const float4*)&g[f];
    float4 bei = *(const float4*)&be[f];
    acc.x = fmaxf((acc.x + bi.x) * gi.x * bns + bei.x, 0.0f);
    acc.y = fmaxf((acc.y + bi.y) * gi.y * bns + bei.y, 0.0f);
    acc.z = fmaxf((acc.z + bi.z) * gi.z * bns + bei.z, 0.0f);
    acc.w = fmaxf((acc.w + bi.w) * gi.w * bns + bei.w, 0.0f);
  }
  *(uint2*)&hout[(size_t)c * 256 + f] = pack_bf4(acc);
}

// D=128: two nodes per wave (half-wave x 4 feats, 8B/lane).
// EPI 0: plain bf16 store. EPI 2: +bias, log_softmax -> fp32 out.
template <int EPI>
__global__ __launch_bounds__(256) void agg128_kernel(
    const uint16_t* __restrict__ hin, void* __restrict__ hout_,
    const int* __restrict__ off, const unsigned int* __restrict__ csr4,
    const float* __restrict__ dinv, const float* __restrict__ bias, int n) {
  const int lane = threadIdx.x & 63;
  const int sub = lane & 31;
  const int hbase = lane & 32;
  const int c = blockIdx.x * 8 + (threadIdx.x >> 6) * 2 + (lane >> 5);
  const bool active = (c < n);
  const int f = sub * 4;

  int e0 = 0, e1 = 0;
  float di = 0.0f;
  float4 acc = make_float4(0.f, 0.f, 0.f, 0.f);
  if (active) {
    e0 = off[c]; e1 = off[c + 1];
    di = dinv[c];
    float4 self = unpack_bf4(*(const uint2*)&hin[(size_t)c * 128 + f]);
    acc = make_float4(self.x * di, self.y * di, self.z * di, self.w * di);
  }
  int nch = (e1 - e0 + 31) >> 5;
  nch = max(nch, __shfl(nch, lane ^ 32));

  for (int ch = 0; ch < nch; ++ch) {
    int idx = e0 + ch * 32 + sub;
    unsigned int ev = 0u;
    if (active && idx < e1) ev = __builtin_nontemporal_load(&csr4[idx]);
    int m = e1 - (e0 + ch * 32);
    m = m < 0 ? 0 : (m > 32 ? 32 : m);
    int mMax = max(m, __shfl(m, lane ^ 32));
    const int nG = (mMax + 3) >> 2;
    for (int gI = 0; gI < nG; ++gI) {
      int e_ = hbase + gI * 4;
      unsigned int ea = __shfl(ev, e_, 64);
      unsigned int eb = __shfl(ev, e_ + 1, 64);
      unsigned int ec = __shfl(ev, e_ + 2, 64);
      unsigned int ed = __shfl(ev, e_ + 3, 64);
      int s0 = (int)(ea & 0xffffu); float v0 = f16tof(ea >> 16);
      int s1 = (int)(eb & 0xffffu); float v1 = f16tof(eb >> 16);
      int sB = (int)(ec & 0xffffu); float v2 = f16tof(ec >> 16);
      int s3 = (int)(ed & 0xffffu); float v3 = f16tof(ed >> 16);
      float4 h0 = unpack_bf4(*(const uint2*)&hin[(size_t)s0 * 128 + f]);
      float4 h1 = unpack_bf4(*(const uint2*)&hin[(size_t)s1 * 128 + f]);
      float4 h2 = unpack_bf4(*(const uint2*)&hin[(size_t)sB * 128 + f]);
      float4 h3 = unpack_bf4(*(const uint2*)&hin[(size_t)s3 * 128 + f]);
      acc.x += v0 * h0.x + v1 * h1.x + v2 * h2.x + v3 * h3.x;
      acc.y += v0 * h0.y + v1 * h1.y + v2 * h2.y + v3 * h3.y;
      acc.z += v0 * h0.z + v1 * h1.z + v2 * h2.z + v3 * h3.z;
      acc.w += v0 * h0.w + v1 * h1.w + v2 * h2.w + v3 * h3.w;
    }
  }

  acc.x *= di; acc.y *= di; acc.z *= di; acc.w *= di;  // final dinv_c
  if (EPI == 0) {
    uint16_t* hout = (uint16_t*)hout_;
    if (active) *(uint2*)&hout[(size_t)c * 128 + f] = pack_bf4(acc);
  } else {
    float* hout = (float*)hout_;
    float4 bi = active ? *(const float4*)&bias[f] : make_float4(0.f, 0.f, 0.f, 0.f);
    float tx = acc.x + bi.x, ty = acc.y + bi.y, tz = acc.z + bi.z, tw = acc.w + bi.w;
    float mx = fmaxf(fmaxf(tx, ty), fmaxf(tz, tw));
#pragma unroll
    for (int s = 1; s < 32; s <<= 1) mx = fmaxf(mx, __shfl_xor(mx, s, 64));
    float ex = expf(tx - mx) + expf(ty - mx) + expf(tz - mx) + expf(tw - mx);
#pragma unroll
    for (int s = 1; s < 32; s <<= 1) ex += __shfl_xor(ex, s, 64);
    float lse = logf(ex) + mx;
    if (active) {
      float4 res = make_float4(tx - lse, ty - lse, tz - lse, tw - lse);
      *(float4*)&hout[(size_t)c * 128 + f] = res;
    }
  }
}

// ---------------------------------------------------------------- MFMA GEMM
// B-stationary: wave holds B-frags for its col group across all K in registers,
// streams 16-row A-tiles with depth-2 prefetch; 4 waves/block share A rows.
template <int K, int NC, int EPI>
__global__ __launch_bounds__(256) void mfma_gemm_kernel(
    const uint16_t* __restrict__ A, const uint16_t* __restrict__ WT,
    uint16_t* __restrict__ Cb, int M, int tpb,
    const float* __restrict__ bias, const float* __restrict__ g,
    const float* __restrict__ be) {
  constexpr int CW = NC / 4;
  constexpr int NT = CW / 16;
  constexpr int KS = K / 32;
  const int lane = threadIdx.x & 63;
  const int wave = threadIdx.x >> 6;
  const int quad = lane >> 4;
  const int l16 = lane & 15;
  const int col0 = wave * CW;

  const int tiles = (M + 15) >> 4;
  int t0 = blockIdx.x * tpb;
  if (t0 >= tiles) return;
  int t1 = min(t0 + tpb, tiles);

  v8bf b[KS][NT];
#pragma unroll
  for (int ks = 0; ks < KS; ++ks)
#pragma unroll
    for (int nt = 0; nt < NT; ++nt)
      b[ks][nt] = *(const v8bf*)(WT + (size_t)(col0 + nt * 16 + l16) * K +
                                 ks * 32 + quad * 8);

  float sc[NT], o1[NT], o2[NT];
  if (EPI == 1) {
    const float bns = rsqrtf(1.0f + GCN_BN_EPS);
#pragma unroll
    for (int nt = 0; nt < NT; ++nt) {
      int col = col0 + nt * 16 + l16;
      sc[nt] = g[col] * bns; o1[nt] = bias[col]; o2[nt] = be[col];
    }
  }

  v8bf a[KS], an[KS];
  {
    int arow = min(t0 * 16 + l16, M - 1);
    const uint16_t* Ap = A + (size_t)arow * K + quad * 8;
#pragma unroll
    for (int ks = 0; ks < KS; ++ks) a[ks] = *(const v8bf*)(Ap + ks * 32);
  }
  for (int t = t0; t < t1; ++t) {
    if (t + 1 < t1) {
      int arow = min((t + 1) * 16 + l16, M - 1);
      const uint16_t* Ap = A + (size_t)arow * K + quad * 8;
#pragma unroll
      for (int ks = 0; ks < KS; ++ks) an[ks] = *(const v8bf*)(Ap + ks * 32);
    }
    v4f acc[NT];
#pragma unroll
    for (int nt = 0; nt < NT; ++nt) acc[nt] = (v4f){0.f, 0.f, 0.f, 0.f};
#pragma unroll
    for (int ks = 0; ks < KS; ++ks)
#pragma unroll
      for (int nt = 0; nt < NT; ++nt)
        acc[nt] = __builtin_amdgcn_mfma_f32_16x16x32_bf16(a[ks], b[ks][nt],
                                                          acc[nt], 0, 0, 0);
    const int row0 = t * 16 + quad * 4;
#pragma unroll
    for (int nt = 0; nt < NT; ++nt) {
      const int col = col0 + nt * 16 + l16;
#pragma unroll
      for (int r = 0; r < 4; ++r) {
        int row = row0 + r;
        if (row < M) {
          float v = acc[nt][r];
          if (EPI == 1) v = fmaxf((v + o1[nt]) * sc[nt] + o2[nt], 0.0f);
          Cb[(size_t)row * NC + col] = f2bf(v);
        }
      }
    }
#pragma unroll
    for (int ks = 0; ks < KS; ++ks) a[ks] = an[ks];
  }
}

// ---------------------------------------------------------------- launch

static inline char* carve(char*& p, size_t bytes) {
  char* r = p;
  p += (bytes + 255) & ~(size_t)255;
  return r;
}

extern "C" void kernel_launch(void* const* d_in, const int* in_sizes, int n_in,
                              void* d_out, int out_size, void* d_ws, size_t ws_size,
                              hipStream_t stream) {
  const int N = in_sizes[0] / 128;
  const int E = in_sizes[2];

  const float* x  = (const float*)d_in[0];
  const int*   ei = (const int*)d_in[1];
  const float* ew = (const float*)d_in[2];
  const float* W0 = (const float*)d_in[3];
  const float* b0 = (const float*)d_in[4];
  const float* W1 = (const float*)d_in[5];
  const float* b1 = (const float*)d_in[6];
  const float* Wl = (const float*)d_in[7];
  const float* bl = (const float*)d_in[8];
  const float* g0 = (const float*)d_in[9];
  const float* be0 = (const float*)d_in[10];
  const float* g1 = (const float*)d_in[11];
  const float* be1 = (const float*)d_in[12];
  float* out = (float*)d_out;

  const int nw = (N + 3) / 4;  // histogram words (N % 4 == 0 for N=50000)

  char* p = (char*)d_ws;
  float*        dinv  = (float*)carve(p, (size_t)N * 4);
  float*        degw  = (float*)carve(p, (size_t)N * 4);
  unsigned int* cntw  = (unsigned int*)carve(p, (size_t)nw * 4);
  int*          off   = (int*)carve(p, (size_t)(N + 1) * 4);
  int*          bsum  = (int*)carve(p, 1024 * 4);
  int*          col_  = (int*)carve(p, (size_t)E * 4);
  uint2*        pk    = (uint2*)carve(p, (size_t)E * 8);
  unsigned int* csr4  = (unsigned int*)carve(p, (size_t)E * 4);
  unsigned int* histw = (unsigned int*)carve(p, (size_t)NB_CHUNK * nw * 4);
  uint16_t*     xb16  = (uint16_t*)carve(p, (size_t)N * 128 * 2);
  uint16_t*     bufR  = (uint16_t*)carve(p, (size_t)N * 128 * 2);
  uint16_t*     bufP  = (uint16_t*)carve(p, (size_t)N * 256 * 2);
  uint16_t*     bufQ  = (uint16_t*)carve(p, (size_t)N * 256 * 2);
  uint16_t*     W0t   = (uint16_t*)carve(p, (size_t)128 * 256 * 2);
  uint16_t*     W1t   = (uint16_t*)carve(p, (size_t)256 * 256 * 2);
  uint16_t*     Wlt   = (uint16_t*)carve(p, (size_t)256 * 128 * 2);

  const int TB = 256;
  const int gW4 = (N + 3) / 4;          // agg256: 4 nodes/block
  const int gW8 = (N + 7) / 8;          // agg128: 8 nodes/block
  const int tiles = (N + 15) / 16;
  const int TPB = 8;                    // row-tiles per block
  const int gG = (tiles + TPB - 1) / TPB;
  const size_t ldsU8 = (size_t)nw * 4;  // 50KB u8-packed bins
  const int nB = (nw + 255) / 256;      // scan blocks (49 <= 64, required)
  const int convT0 = N * 32;            // x float4 groups
  const int convTot = convT0 + 128 * 256 + 256 * 256 + 256 * 128 + N;  // +dinv
  const int convB = (convTot + TB - 1) / TB;

  // CSC build: u8-chunked build (+degw atomics), scan+conv+dinv, fused
  // scan3+base, single-pass fill writing csr4 (u16 src | f16 dinv_s*w)
  hipMemsetAsync(degw, 0, (size_t)N * 4, stream);
  build_hist_kernel<<<NB_CHUNK, TB, ldsU8, stream>>>(ei, ew, col_, pk, histw,
                                                     degw, E, N);
  scan1_conv_kernel<<<nB + convB, TB, 0, stream>>>(histw, cntw, bsum, nw, nB,
                                                   x, xb16, W0, W0t, W1, W1t,
                                                   Wl, Wlt, degw, dinv,
                                                   convT0, convTot);
  scan3_base_kernel<<<nB, TB, 0, stream>>>(cntw, bsum, off, histw, nw, nB, N, E);
  fill_kernel<<<NB_CHUNK, TB, ldsU8, stream>>>(col_, pk, off, histw, dinv,
                                               csr4, E, N);

  // layer 0: agg(xb16,128) -> bufR; MFMA GEMM0 +BN0+ReLU -> bufP[N,256]
  agg128_kernel<0><<<gW8, 256, 0, stream>>>(xb16, bufR, off, csr4, dinv,
                                            nullptr, N);
  mfma_gemm_kernel<128, 256, 1><<<gG, 256, 0, stream>>>(bufR, W0t, bufP, N, TPB,
                                                        b0, g0, be0);
  // layer 1: GEMM1 -> bufQ; agg256 +b1+BN1+ReLU -> bufP
  mfma_gemm_kernel<256, 256, 0><<<gG, 256, 0, stream>>>(bufP, W1t, bufQ, N, TPB,
                                                        nullptr, nullptr, nullptr);
  agg256_kernel<1><<<gW4, 256, 0, stream>>>(bufQ, bufP, off, csr4, dinv,
                                            b1, g1, be1, N);
  // layer 2: GEMM2 -> bufR; agg128 +bl+log_softmax -> out (fp32)
  mfma_gemm_kernel<256, 128, 0><<<gG, 256, 0, stream>>>(bufP, Wlt, bufR, N, TPB,
                                                        nullptr, nullptr, nullptr);
  agg128_kernel<2><<<gW8, 256, 0, stream>>>(bufR, out, off, csr4, dinv, bl, N);
}